// Round 7
// baseline (2419.667 us; speedup 1.0000x reference)
//
#include <hip/hip_runtime.h>
#include <math.h>

// Problem constants
#define NNODES   32768          // B*NG
#define NEDGES   262144         // B*EG
#define EATOT    (NEDGES + NNODES)  // edges + self loops = 294912
#define NB       128            // graphs
#define NGR      256            // nodes per graph
#define KKEEP    128            // top-k per graph
#define F1DIM    256
#define DNODE    64
#define DEDGE    32

// ---------------------------------------------------------------------------
// XLA/Eigen f32 tanh emulation (generic_fast_tanh_float / EmitTanh):
// clamps to EXACTLY +-1.0 for |x| > 7.90531110763549805 -> creates exact ties
// at 1.0 among saturated SAG scores, which lax.top_k breaks by index.
// ---------------------------------------------------------------------------
__device__ __forceinline__ float xla_tanhf(float x) {
    float ax = fabsf(x);
    if (ax < 0.0004f) return x;
    if (ax > 7.90531110763549805f) return copysignf(1.0f, x);
    float x2 = __fmul_rn(x, x);
    float p = -2.76076847742355e-16f;
    p = fmaf(p, x2, 2.00018790482477e-13f);
    p = fmaf(p, x2, -8.60467152213735e-11f);
    p = fmaf(p, x2, 5.12229709037114e-08f);
    p = fmaf(p, x2, 1.48572235717979e-05f);
    p = fmaf(p, x2, 6.37261928875436e-04f);
    p = fmaf(p, x2, 4.89352455891786e-03f);
    p = __fmul_rn(x, p);
    float q = 1.19825839466702e-06f;
    q = fmaf(q, x2, 1.18534705686654e-04f);
    q = fmaf(q, x2, 2.26843463243900e-03f);
    q = fmaf(q, x2, 4.89352518554385e-03f);
    return __fdiv_rn(p, q);
}

// ---------------------------------------------------------------------------
// CSR build
// ---------------------------------------------------------------------------
__global__ void count_kernel(const int* __restrict__ ei, int* __restrict__ deg) {
    int t = blockIdx.x * 256 + threadIdx.x;
    if (t < NEDGES) atomicAdd(&deg[ei[NEDGES + t]], 1);
}

__global__ void scan_kernel(const int* __restrict__ deg, int* __restrict__ rowstart,
                            int* __restrict__ fill) {
    __shared__ int sh[1024];
    int t = threadIdx.x;
    int base = t * 32;
    int local[32];
    int s = 0;
#pragma unroll
    for (int i = 0; i < 32; i++) { local[i] = deg[base + i]; s += local[i]; }
    sh[t] = s;
    __syncthreads();
    for (int off = 1; off < 1024; off <<= 1) {
        int v = 0;
        if (t >= off) v = sh[t - off];
        __syncthreads();
        if (t >= off) sh[t] += v;
        __syncthreads();
    }
    int run = sh[t] - s;   // exclusive prefix
#pragma unroll
    for (int i = 0; i < 32; i++) {
        rowstart[base + i] = run;
        fill[base + i] = run;
        run += local[i];
    }
    if (t == 1023) rowstart[NNODES] = run;
}

__global__ void scatter_kernel(const int* __restrict__ ei, int* __restrict__ fill,
                               int* __restrict__ csr) {
    int t = blockIdx.x * 256 + threadIdx.x;
    if (t < NEDGES) {
        int d = ei[NEDGES + t];
        int slot = atomicAdd(&fill[d], 1);
        csr[slot] = t;
    }
}

// Sort each node's incoming-edge list ascending (np.add.at edge order).
__global__ void sortcsr_kernel(const int* __restrict__ rowstart, int* __restrict__ csr) {
    int n = blockIdx.x * 256 + threadIdx.x;
    if (n >= NNODES) return;
    int s0 = rowstart[n], s1 = rowstart[n + 1];
    for (int i = s0 + 1; i < s1; i++) {
        int v = csr[i];
        int j = i - 1;
        while (j >= s0 && csr[j] > v) { csr[j + 1] = csr[j]; j--; }
        csr[j + 1] = v;
    }
}

// loop_attr[n][c] = mean of incoming edge_attr — fp32 sequential in edge order
__global__ void loopattr_kernel(const int* __restrict__ rowstart, const int* __restrict__ csr,
                                const float* __restrict__ eattr, float* __restrict__ loop_attr) {
    int t = blockIdx.x * 256 + threadIdx.x;   // N*32 threads
    int n = t >> 5, c = t & 31;
    int s0 = rowstart[n], s1 = rowstart[n + 1];
    float sum = 0.f;
    for (int i = s0; i < s1; i++) sum = __fadd_rn(sum, eattr[(size_t)csr[i] * DEDGE + c]);
    float cnt = (float)(s1 - s0);
    loop_attr[t] = __fdiv_rn(sum, fmaxf(cnt, 1.f));
}

// ---------------------------------------------------------------------------
// Dense transforms: per output element, fp32 single accumulator, k ascending,
// fused FMA (sgemm semantics); bias added after.
// ---------------------------------------------------------------------------
template<int KD>
__global__ __launch_bounds__(256) void gemm_lr_kernel(
    const float* __restrict__ X,
    const float* __restrict__ Wl, const float* __restrict__ bl,
    const float* __restrict__ Wr, const float* __restrict__ br,
    float* __restrict__ outL, float* __restrict__ outR) {
    constexpr int NPB = 8;
    __shared__ float xs[NPB * KD];
    int n0 = blockIdx.x * NPB;
    int c = threadIdx.x;
    for (int i = c; i < NPB * KD; i += 256) xs[i] = X[(size_t)n0 * KD + i];
    __syncthreads();
    float accL[NPB], accR[NPB];
#pragma unroll
    for (int m = 0; m < NPB; m++) { accL[m] = 0.f; accR[m] = 0.f; }
    for (int k = 0; k < KD; k++) {
        float wl = Wl[k * F1DIM + c];
        float wr = Wr[k * F1DIM + c];
#pragma unroll
        for (int m = 0; m < NPB; m++) {
            float xv = xs[m * KD + k];
            accL[m] = fmaf(xv, wl, accL[m]);
            accR[m] = fmaf(xv, wr, accR[m]);
        }
    }
    float blc = bl[c], brc = br[c];
#pragma unroll
    for (int m = 0; m < NPB; m++) {
        outL[(size_t)(n0 + m) * F1DIM + c] = __fadd_rn(accL[m], blc);
        outR[(size_t)(n0 + m) * F1DIM + c] = __fadd_rn(accR[m], brc);
    }
}

// ---------------------------------------------------------------------------
// Edge logits:
//   ef    = eattr@We      : fp32 seq-k FMA, k ascending
//   m     = (xl[src]+xr[dst])+ef  : fp32 left-assoc adds
//   lk    = leaky_relu(m,0.2)
//   logit = einsum over c : 4 strided partial sums (mul+add), c ascending,
//           combined ((s0+s2)+(s1+s3)).
// ---------------------------------------------------------------------------
template<int H>
__global__ __launch_bounds__(256) void logits_kernel(
    const int* __restrict__ ei,
    const float* __restrict__ eattr, const float* __restrict__ loop_attr,
    const float* __restrict__ xl, const float* __restrict__ xr,
    const float* __restrict__ We, const float* __restrict__ att,
    float* __restrict__ logits) {
    __shared__ float WeS[DEDGE * F1DIM];
    __shared__ float attS[F1DIM];
    int t = threadIdx.x;
    for (int i = t; i < DEDGE * F1DIM; i += 256) WeS[i] = We[i];
    attS[t] = att[t];
    __syncthreads();

    int lane = t & 63;
    int wid = (blockIdx.x * 256 + t) >> 6;
    int nw = (gridDim.x * 256) >> 6;
    const float4* WeS4 = (const float4*)WeS;
    float4 a4 = ((const float4*)attS)[lane];

    for (int e = wid; e < EATOT; e += nw) {
        int s, d;
        const float* ea;
        if (e < NEDGES) {
            s = ei[e]; d = ei[NEDGES + e];
            ea = eattr + (size_t)e * DEDGE;
        } else {
            s = e - NEDGES; d = s;
            ea = loop_attr + (size_t)(e - NEDGES) * DEDGE;
        }
        float eav = ea[lane & 31];
        float ef0 = 0.f, ef1 = 0.f, ef2 = 0.f, ef3 = 0.f;
#pragma unroll
        for (int k = 0; k < DEDGE; k++) {
            float eak = __shfl(eav, k, 64);
            float4 w4 = WeS4[k * 64 + lane];
            ef0 = fmaf(eak, w4.x, ef0);
            ef1 = fmaf(eak, w4.y, ef1);
            ef2 = fmaf(eak, w4.z, ef2);
            ef3 = fmaf(eak, w4.w, ef3);
        }
        float4 l4 = ((const float4*)(xl + (size_t)s * F1DIM))[lane];
        float4 r4 = ((const float4*)(xr + (size_t)d * F1DIM))[lane];
        float mv, lk;
        float p0, p1, p2, p3;
        mv = __fadd_rn(__fadd_rn(l4.x, r4.x), ef0);
        lk = mv > 0.f ? mv : __fmul_rn(0.2f, mv);
        p0 = __fmul_rn(lk, a4.x);
        mv = __fadd_rn(__fadd_rn(l4.y, r4.y), ef1);
        lk = mv > 0.f ? mv : __fmul_rn(0.2f, mv);
        p1 = __fmul_rn(lk, a4.y);
        mv = __fadd_rn(__fadd_rn(l4.z, r4.z), ef2);
        lk = mv > 0.f ? mv : __fmul_rn(0.2f, mv);
        p2 = __fmul_rn(lk, a4.z);
        mv = __fadd_rn(__fadd_rn(l4.w, r4.w), ef3);
        lk = mv > 0.f ? mv : __fmul_rn(0.2f, mv);
        p3 = __fmul_rn(lk, a4.w);

        if (H == 2) {
            float sA0 = 0.f, sA1 = 0.f, sA2 = 0.f, sA3 = 0.f;
            float sB0 = 0.f, sB1 = 0.f, sB2 = 0.f, sB3 = 0.f;
            for (int L = 0; L < 32; L++) {
                sA0 = __fadd_rn(sA0, __shfl(p0, L, 64));
                sA1 = __fadd_rn(sA1, __shfl(p1, L, 64));
                sA2 = __fadd_rn(sA2, __shfl(p2, L, 64));
                sA3 = __fadd_rn(sA3, __shfl(p3, L, 64));
                sB0 = __fadd_rn(sB0, __shfl(p0, L + 32, 64));
                sB1 = __fadd_rn(sB1, __shfl(p1, L + 32, 64));
                sB2 = __fadd_rn(sB2, __shfl(p2, L + 32, 64));
                sB3 = __fadd_rn(sB3, __shfl(p3, L + 32, 64));
            }
            float ra = __fadd_rn(__fadd_rn(sA0, sA2), __fadd_rn(sA1, sA3));
            float rb = __fadd_rn(__fadd_rn(sB0, sB2), __fadd_rn(sB1, sB3));
            if (lane == 0) {
                logits[(size_t)e * 2 + 0] = ra;
                logits[(size_t)e * 2 + 1] = rb;
            }
        } else {
            float s0 = 0.f, s1 = 0.f, s2 = 0.f, s3 = 0.f;
            for (int L = 0; L < 64; L++) {
                s0 = __fadd_rn(s0, __shfl(p0, L, 64));
                s1 = __fadd_rn(s1, __shfl(p1, L, 64));
                s2 = __fadd_rn(s2, __shfl(p2, L, 64));
                s3 = __fadd_rn(s3, __shfl(p3, L, 64));
            }
            float r = __fadd_rn(__fadd_rn(s0, s2), __fadd_rn(s1, s3));
            if (lane == 0) logits[e] = r;
        }
    }
}

// ---------------------------------------------------------------------------
// Segment softmax per (node, head), fp32, edge order: originals ascending,
// self-loop LAST. exp correctly rounded via double.
// ---------------------------------------------------------------------------
template<int H>
__global__ void softmax_kernel(const int* __restrict__ rowstart, const int* __restrict__ csr,
                               const float* __restrict__ logits, float* __restrict__ w) {
    int t = blockIdx.x * 256 + threadIdx.x;
    if (t >= NNODES * H) return;
    int n = t / H;
    int h = t - n * H;
    int s0 = rowstart[n], s1 = rowstart[n + 1];
    float lself = logits[(size_t)(NEDGES + n) * H + h];
    float mx = lself;
    for (int i = s0; i < s1; i++) {
        float l = logits[(size_t)csr[i] * H + h];
        mx = fmaxf(mx, l);
    }
    float den = 0.f;
    for (int i = s0; i < s1; i++) {
        float ex = (float)exp((double)__fsub_rn(logits[(size_t)csr[i] * H + h], mx));
        den = __fadd_rn(den, ex);
    }
    float exs = (float)exp((double)__fsub_rn(lself, mx));
    den = __fadd_rn(den, exs);
    for (int i = s0; i < s1; i++) {
        size_t idx = (size_t)csr[i] * H + h;
        float ex = (float)exp((double)__fsub_rn(logits[idx], mx));
        w[idx] = __fdiv_rn(ex, den);
    }
    w[(size_t)(NEDGES + n) * H + h] = __fdiv_rn(exs, den);
}

// ---------------------------------------------------------------------------
// Aggregation: out[n,c] = (Σ_e fp32(alpha_e * xl[src_e,c])) + bout[c]
// fp32 sequential, originals ascending then self LAST, no FMA contraction.
// ---------------------------------------------------------------------------
template<int H, bool RELU>
__global__ __launch_bounds__(256) void agg_kernel(
    const int* __restrict__ ei, const int* __restrict__ rowstart, const int* __restrict__ csr,
    const float* __restrict__ w, const float* __restrict__ xl,
    const float* __restrict__ bout, float* __restrict__ out) {
    int n = blockIdx.x;
    int c = threadIdx.x;
    int h = (H == 2) ? (c >> 7) : 0;
    float acc = 0.f;
    int s0 = rowstart[n], s1 = rowstart[n + 1];
    for (int i = s0; i < s1; i++) {
        int e = csr[i];
        int sn = ei[e];
        float p = __fmul_rn(w[(size_t)e * H + h], xl[(size_t)sn * F1DIM + c]);
        acc = __fadd_rn(acc, p);
    }
    float pself = __fmul_rn(w[(size_t)(NEDGES + n) * H + h], xl[(size_t)n * F1DIM + c]);
    acc = __fadd_rn(acc, pself);
    acc = __fadd_rn(acc, bout[c]);
    if (RELU) acc = fmaxf(acc, 0.f);
    out[(size_t)n * F1DIM + c] = acc;
}

// ---------------------------------------------------------------------------
// SAG scorer with XLA-tanh:
//   aggv[n] = Σ_{original e:dst=n} h2[src_e]
//   score = xla_tanhf( (aggv·Wrel + brel) + h2·Wroot )
// ---------------------------------------------------------------------------
__global__ __launch_bounds__(256) void aggvec_kernel(
    const int* __restrict__ ei, const int* __restrict__ rowstart, const int* __restrict__ csr,
    const float* __restrict__ h2, float* __restrict__ aggv) {
    int n = blockIdx.x;
    int c = threadIdx.x;
    float acc = 0.f;
    int s0 = rowstart[n], s1 = rowstart[n + 1];
    for (int i = s0; i < s1; i++) {
        int sn = ei[csr[i]];
        acc = __fadd_rn(acc, h2[(size_t)sn * F1DIM + c]);
    }
    aggv[(size_t)n * F1DIM + c] = acc;
}

__global__ __launch_bounds__(256) void score_dots_kernel(
    const float* __restrict__ h2, const float* __restrict__ aggv,
    const float* __restrict__ Wrel, const float* __restrict__ Wroot,
    const float* __restrict__ brel, float* __restrict__ score) {
    __shared__ float wr[256], wo[256];
    int t = threadIdx.x;
    wr[t] = Wrel[t];
    wo[t] = Wroot[t];
    __syncthreads();
    int n = blockIdx.x * 256 + t;
    const float* hv = h2 + (size_t)n * F1DIM;
    const float* av = aggv + (size_t)n * F1DIM;
    float s1 = 0.f, s2 = 0.f;
    for (int c = 0; c < F1DIM; c++) {
        s1 = fmaf(av[c], wr[c], s1);
        s2 = fmaf(hv[c], wo[c], s2);
    }
    float u = __fadd_rn(__fadd_rn(s1, brel[0]), s2);
    score[n] = xla_tanhf(u);   // XLA/Eigen tanh: saturates to +-1.0 at |u|>7.905
}

// ---------------------------------------------------------------------------
// Per-graph top-k (bitonic, fp32 score desc / index asc = lax.top_k stable)
// + head: xk[c] = fp32(h2[idx][c]*sv); z = seq-FMA(xk,Wlin)+blin; sigmoid.
// ---------------------------------------------------------------------------
__global__ __launch_bounds__(256) void topk_kernel(
    const float* __restrict__ score, const float* __restrict__ h2,
    const float* __restrict__ Wlin, const float* __restrict__ blin,
    float* __restrict__ out) {
    __shared__ float sv[256];
    __shared__ int si[256];
    __shared__ float wl[256];
    int t = threadIdx.x;
    int g = blockIdx.x;
    sv[t] = score[g * NGR + t];
    si[t] = t;
    wl[t] = Wlin[t];
    __syncthreads();
    for (int k = 2; k <= 256; k <<= 1) {
        for (int j = k >> 1; j > 0; j >>= 1) {
            int ixj = t ^ j;
            if (ixj > t) {
                float va = sv[t], vb = sv[ixj];
                int ia = si[t], ib = si[ixj];
                bool before = (va > vb) || (va == vb && ia < ib);  // stable: idx asc
                bool up = ((t & k) == 0);
                if (up ? !before : before) {
                    sv[t] = vb; sv[ixj] = va;
                    si[t] = ib; si[ixj] = ia;
                }
            }
            __syncthreads();
        }
    }
    if (t < KKEEP) {
        float v = sv[t];
        int idx = si[t];
        const float* hv = h2 + (size_t)(g * NGR + idx) * F1DIM;
        float acc = 0.f;
        for (int c = 0; c < F1DIM; c++) {
            float xc = __fmul_rn(hv[c], v);
            acc = fmaf(xc, wl[c], acc);
        }
        float z = __fadd_rn(acc, blin[0]);
        out[g * KKEEP + t] = (float)(1.0 / (1.0 + exp(-(double)z)));
    }
}

// ---------------------------------------------------------------------------
extern "C" void kernel_launch(void* const* d_in, const int* in_sizes, int n_in,
                              void* d_out, int out_size, void* d_ws, size_t ws_size,
                              hipStream_t stream) {
    const float* x        = (const float*)d_in[0];
    const int*   ei       = (const int*)d_in[1];
    const float* eattr    = (const float*)d_in[2];
    // d_in[3] = batch (unused; nodes are contiguous per graph)
    const float* Wl1  = (const float*)d_in[4];
    const float* bl1  = (const float*)d_in[5];
    const float* Wr1  = (const float*)d_in[6];
    const float* br1  = (const float*)d_in[7];
    const float* We1  = (const float*)d_in[8];
    const float* att1 = (const float*)d_in[9];
    const float* bout1= (const float*)d_in[10];
    const float* Wl2  = (const float*)d_in[11];
    const float* bl2  = (const float*)d_in[12];
    const float* Wr2  = (const float*)d_in[13];
    const float* br2  = (const float*)d_in[14];
    const float* We2  = (const float*)d_in[15];
    const float* att2 = (const float*)d_in[16];
    const float* bout2= (const float*)d_in[17];
    const float* Wrel = (const float*)d_in[18];
    const float* brel = (const float*)d_in[19];
    const float* Wroot= (const float*)d_in[20];
    const float* Wlin = (const float*)d_in[21];
    const float* blin = (const float*)d_in[22];
    float* out = (float*)d_out;

    // workspace carve
    char* p = (char*)d_ws;
    auto alloc = [&](size_t bytes) {
        void* r = (void*)p;
        p += (bytes + 255) & ~(size_t)255;
        return r;
    };
    int*   deg      = (int*)alloc(NNODES * 4);
    int*   rowstart = (int*)alloc((NNODES + 1) * 4);
    int*   fill     = (int*)alloc(NNODES * 4);
    int*   csr      = (int*)alloc(NEDGES * 4);
    float* loop_attr= (float*)alloc((size_t)NNODES * DEDGE * 4);
    float* bufA     = (float*)alloc((size_t)NNODES * F1DIM * 4);   // xl / aggv
    float* bufB     = (float*)alloc((size_t)NNODES * F1DIM * 4);   // xr
    float* bufC     = (float*)alloc((size_t)NNODES * F1DIM * 4);   // h1 then h2
    float* logitsB  = (float*)alloc((size_t)EATOT * 2 * 4);
    float* wB       = (float*)alloc((size_t)EATOT * 2 * 4);
    float* scoreV   = (float*)alloc(NNODES * 4);

    // CSR build (deterministic after sort)
    hipMemsetAsync(deg, 0, NNODES * 4, stream);
    count_kernel<<<NEDGES / 256, 256, 0, stream>>>(ei, deg);
    scan_kernel<<<1, 1024, 0, stream>>>(deg, rowstart, fill);
    scatter_kernel<<<NEDGES / 256, 256, 0, stream>>>(ei, fill, csr);
    sortcsr_kernel<<<NNODES / 256, 256, 0, stream>>>(rowstart, csr);
    loopattr_kernel<<<NNODES * DEDGE / 256, 256, 0, stream>>>(rowstart, csr, eattr, loop_attr);

    // ---- layer 1 (heads=2) ----
    gemm_lr_kernel<DNODE><<<NNODES / 8, 256, 0, stream>>>(x, Wl1, bl1, Wr1, br1, bufA, bufB);
    logits_kernel<2><<<2048, 256, 0, stream>>>(ei, eattr, loop_attr, bufA, bufB, We1, att1, logitsB);
    softmax_kernel<2><<<(NNODES * 2) / 256, 256, 0, stream>>>(rowstart, csr, logitsB, wB);
    agg_kernel<2, true><<<NNODES, 256, 0, stream>>>(ei, rowstart, csr, wB, bufA, bout1, bufC);

    // ---- layer 2 (heads=1) ----
    gemm_lr_kernel<F1DIM><<<NNODES / 8, 256, 0, stream>>>(bufC, Wl2, bl2, Wr2, br2, bufA, bufB);
    logits_kernel<1><<<2048, 256, 0, stream>>>(ei, eattr, loop_attr, bufA, bufB, We2, att2, logitsB);
    softmax_kernel<1><<<NNODES / 256, 256, 0, stream>>>(rowstart, csr, logitsB, wB);
    agg_kernel<1, false><<<NNODES, 256, 0, stream>>>(ei, rowstart, csr, wB, bufA, bout2, bufC);

    // ---- SAG pooling + head ----
    aggvec_kernel<<<NNODES, 256, 0, stream>>>(ei, rowstart, csr, bufC, bufA);
    score_dots_kernel<<<NNODES / 256, 256, 0, stream>>>(bufC, bufA, Wrel, Wroot, brel, scoreV);
    topk_kernel<<<NB, 256, 0, stream>>>(scoreV, bufC, Wlin, blin, out);
}

// Round 9
// 1327.922 us; speedup vs baseline: 1.8221x; 1.8221x over previous
//
#include <hip/hip_runtime.h>
#include <math.h>

// Problem constants
#define NNODES   32768          // B*NG
#define NEDGES   262144         // B*EG
#define EATOT    (NEDGES + NNODES)  // edges + self loops = 294912
#define NB       128            // graphs
#define NGR      256            // nodes per graph
#define KKEEP    128            // top-k per graph
#define F1DIM    256
#define DNODE    64
#define DEDGE    32

// ---------------------------------------------------------------------------
// XLA/Eigen f32 tanh emulation: clamps to EXACTLY +-1.0 for |x| > 7.90531...
// Creates exact ties at 1.0 among saturated SAG scores; top_k breaks by index.
// DO NOT REPLACE with tanhf. DO NOT PERTURB upstream arithmetic: clamp
// membership is sensitive to ~1e-4 noise in u (round-8 lesson).
// ---------------------------------------------------------------------------
__device__ __forceinline__ float xla_tanhf(float x) {
    float ax = fabsf(x);
    if (ax < 0.0004f) return x;
    if (ax > 7.90531110763549805f) return copysignf(1.0f, x);
    float x2 = __fmul_rn(x, x);
    float p = -2.76076847742355e-16f;
    p = fmaf(p, x2, 2.00018790482477e-13f);
    p = fmaf(p, x2, -8.60467152213735e-11f);
    p = fmaf(p, x2, 5.12229709037114e-08f);
    p = fmaf(p, x2, 1.48572235717979e-05f);
    p = fmaf(p, x2, 6.37261928875436e-04f);
    p = fmaf(p, x2, 4.89352455891786e-03f);
    p = __fmul_rn(x, p);
    float q = 1.19825839466702e-06f;
    q = fmaf(q, x2, 1.18534705686654e-04f);
    q = fmaf(q, x2, 2.26843463243900e-03f);
    q = fmaf(q, x2, 4.89352518554385e-03f);
    return __fdiv_rn(p, q);
}

__device__ __forceinline__ float lane_bcast(float v, int srclane) {
    return __uint_as_float(__builtin_amdgcn_readlane(__float_as_uint(v), srclane));
}

// ---------------------------------------------------------------------------
// CSR build
// ---------------------------------------------------------------------------
__global__ void count_kernel(const int* __restrict__ ei, int* __restrict__ deg) {
    int t = blockIdx.x * 256 + threadIdx.x;
    if (t < NEDGES) atomicAdd(&deg[ei[NEDGES + t]], 1);
}

__global__ void scan_kernel(const int* __restrict__ deg, int* __restrict__ rowstart,
                            int* __restrict__ fill) {
    __shared__ int sh[1024];
    int t = threadIdx.x;
    int base = t * 32;
    int local[32];
    int s = 0;
#pragma unroll
    for (int i = 0; i < 32; i++) { local[i] = deg[base + i]; s += local[i]; }
    sh[t] = s;
    __syncthreads();
    for (int off = 1; off < 1024; off <<= 1) {
        int v = 0;
        if (t >= off) v = sh[t - off];
        __syncthreads();
        if (t >= off) sh[t] += v;
        __syncthreads();
    }
    int run = sh[t] - s;   // exclusive prefix
#pragma unroll
    for (int i = 0; i < 32; i++) {
        rowstart[base + i] = run;
        fill[base + i] = run;
        run += local[i];
    }
    if (t == 1023) rowstart[NNODES] = run;
}

__global__ void scatter_kernel(const int* __restrict__ ei, int* __restrict__ fill,
                               int* __restrict__ csr) {
    int t = blockIdx.x * 256 + threadIdx.x;
    if (t < NEDGES) {
        int d = ei[NEDGES + t];
        int slot = atomicAdd(&fill[d], 1);
        csr[slot] = t;
    }
}

// Sort each node's incoming-edge list ascending (np.add.at edge order).
__global__ void sortcsr_kernel(const int* __restrict__ rowstart, int* __restrict__ csr) {
    int n = blockIdx.x * 256 + threadIdx.x;
    if (n >= NNODES) return;
    int s0 = rowstart[n], s1 = rowstart[n + 1];
    for (int i = s0 + 1; i < s1; i++) {
        int v = csr[i];
        int j = i - 1;
        while (j >= s0 && csr[j] > v) { csr[j + 1] = csr[j]; j--; }
        csr[j + 1] = v;
    }
}

// loop_attr[n][c] = mean of incoming edge_attr — fp32 sequential in edge order
__global__ void loopattr_kernel(const int* __restrict__ rowstart, const int* __restrict__ csr,
                                const float* __restrict__ eattr, float* __restrict__ loop_attr) {
    int t = blockIdx.x * 256 + threadIdx.x;   // N*32 threads
    int n = t >> 5, c = t & 31;
    int s0 = rowstart[n], s1 = rowstart[n + 1];
    float sum = 0.f;
    for (int i = s0; i < s1; i++) sum = __fadd_rn(sum, eattr[(size_t)csr[i] * DEDGE + c]);
    float cnt = (float)(s1 - s0);
    loop_attr[t] = __fdiv_rn(sum, fmaxf(cnt, 1.f));
}

// ---------------------------------------------------------------------------
// Dense transforms: per output element, fp32 single accumulator, k ascending,
// fused FMA; bias added after. NPB=16 (bit-identical per-element math).
// ---------------------------------------------------------------------------
template<int KD>
__global__ __launch_bounds__(256) void gemm_lr_kernel(
    const float* __restrict__ X,
    const float* __restrict__ Wl, const float* __restrict__ bl,
    const float* __restrict__ Wr, const float* __restrict__ br,
    float* __restrict__ outL, float* __restrict__ outR) {
    constexpr int NPB = 16;
    __shared__ float xs[NPB * KD];
    int n0 = blockIdx.x * NPB;
    int c = threadIdx.x;
    for (int i = c; i < NPB * KD; i += 256) xs[i] = X[(size_t)n0 * KD + i];
    __syncthreads();
    float accL[NPB], accR[NPB];
#pragma unroll
    for (int m = 0; m < NPB; m++) { accL[m] = 0.f; accR[m] = 0.f; }
    for (int k = 0; k < KD; k++) {
        float wl = Wl[k * F1DIM + c];
        float wr = Wr[k * F1DIM + c];
#pragma unroll
        for (int m = 0; m < NPB; m++) {
            float xv = xs[m * KD + k];
            accL[m] = fmaf(xv, wl, accL[m]);
            accR[m] = fmaf(xv, wr, accR[m]);
        }
    }
    float blc = bl[c], brc = br[c];
#pragma unroll
    for (int m = 0; m < NPB; m++) {
        outL[(size_t)(n0 + m) * F1DIM + c] = __fadd_rn(accL[m], blc);
        outR[(size_t)(n0 + m) * F1DIM + c] = __fadd_rn(accR[m], brc);
    }
}

// ---------------------------------------------------------------------------
// Edge logits — BIT-EXACT to round-7 values, cheaper instructions:
//   ef    : seq-k FMA, k ascending (We in REGISTERS, ea via v_readlane)
//   m     : (xl[src]+xr[dst])+ef left-assoc
//   lk    : leaky_relu(m,0.2); p_j = lk*att
//   logit : r7 serial chains — sA_j = sum_{L=0..31} p_j[L], sB_j over L=32..63
//           (H=1: s_j over L=0..63), combine ((s0+s2)+(s1+s3)).
//           Implemented via LDS transpose + broadcast reads (same add order).
// ---------------------------------------------------------------------------
template<int H>
__global__ __launch_bounds__(256) void logits_kernel(
    const int* __restrict__ ei,
    const float* __restrict__ eattr, const float* __restrict__ loop_attr,
    const float* __restrict__ xl, const float* __restrict__ xr,
    const float* __restrict__ We, const float* __restrict__ att,
    float* __restrict__ logits) {
    __shared__ float4 stage[4][64];   // per-wave transpose buffer
    int t = threadIdx.x;
    int lane = t & 63;
    int wv = t >> 6;

    // We -> registers: wreg[k] = We[k][lane*4 .. lane*4+3]
    float4 wreg[DEDGE];
#pragma unroll
    for (int k = 0; k < DEDGE; k++) wreg[k] = ((const float4*)We)[k * 64 + lane];
    float4 a4 = ((const float4*)att)[lane];

    int wid = (blockIdx.x * 256 + t) >> 6;
    int nw = (gridDim.x * 256) >> 6;

    for (int e = wid; e < EATOT; e += nw) {
        int s, d;
        const float* ea;
        if (e < NEDGES) {
            s = ei[e]; d = ei[NEDGES + e];
            ea = eattr + (size_t)e * DEDGE;
        } else {
            s = e - NEDGES; d = s;
            ea = loop_attr + (size_t)(e - NEDGES) * DEDGE;
        }
        float eav = ea[lane & 31];
        float ef0 = 0.f, ef1 = 0.f, ef2 = 0.f, ef3 = 0.f;
#pragma unroll
        for (int k = 0; k < DEDGE; k++) {
            float eak = lane_bcast(eav, k);   // == __shfl(eav,k,64), no LDS op
            ef0 = fmaf(eak, wreg[k].x, ef0);
            ef1 = fmaf(eak, wreg[k].y, ef1);
            ef2 = fmaf(eak, wreg[k].z, ef2);
            ef3 = fmaf(eak, wreg[k].w, ef3);
        }
        float4 l4 = ((const float4*)(xl + (size_t)s * F1DIM))[lane];
        float4 r4 = ((const float4*)(xr + (size_t)d * F1DIM))[lane];
        float mv, lk;
        float4 pv;
        mv = __fadd_rn(__fadd_rn(l4.x, r4.x), ef0);
        lk = mv > 0.f ? mv : __fmul_rn(0.2f, mv);
        pv.x = __fmul_rn(lk, a4.x);
        mv = __fadd_rn(__fadd_rn(l4.y, r4.y), ef1);
        lk = mv > 0.f ? mv : __fmul_rn(0.2f, mv);
        pv.y = __fmul_rn(lk, a4.y);
        mv = __fadd_rn(__fadd_rn(l4.z, r4.z), ef2);
        lk = mv > 0.f ? mv : __fmul_rn(0.2f, mv);
        pv.z = __fmul_rn(lk, a4.z);
        mv = __fadd_rn(__fadd_rn(l4.w, r4.w), ef3);
        lk = mv > 0.f ? mv : __fmul_rn(0.2f, mv);
        pv.w = __fmul_rn(lk, a4.w);

        stage[wv][lane] = pv;             // ds_write_b128 (wave-private; no barrier)

        if (H == 2) {
            // lanes 0..31 accumulate sA chains (L=0..31), lanes 32..63 sB (L=32..63)
            float s0 = 0.f, s1 = 0.f, s2 = 0.f, s3 = 0.f;
            int half = lane & 32;
#pragma unroll
            for (int L = 0; L < 32; L++) {
                float4 v = stage[wv][half + L];   // same-addr broadcast per half
                s0 = __fadd_rn(s0, v.x);
                s1 = __fadd_rn(s1, v.y);
                s2 = __fadd_rn(s2, v.z);
                s3 = __fadd_rn(s3, v.w);
            }
            float r = __fadd_rn(__fadd_rn(s0, s2), __fadd_rn(s1, s3));
            if (lane == 0)  logits[(size_t)e * 2 + 0] = r;
            if (lane == 32) logits[(size_t)e * 2 + 1] = r;
        } else {
            float s0 = 0.f, s1 = 0.f, s2 = 0.f, s3 = 0.f;
#pragma unroll
            for (int L = 0; L < 64; L++) {
                float4 v = stage[wv][L];          // same-addr broadcast, all lanes
                s0 = __fadd_rn(s0, v.x);
                s1 = __fadd_rn(s1, v.y);
                s2 = __fadd_rn(s2, v.z);
                s3 = __fadd_rn(s3, v.w);
            }
            float r = __fadd_rn(__fadd_rn(s0, s2), __fadd_rn(s1, s3));
            if (lane == 0) logits[e] = r;
        }
    }
}

// ---------------------------------------------------------------------------
// Segment softmax per (node, head), fp32, edge order: originals ascending,
// self-loop LAST. exp correctly rounded via double.
// ---------------------------------------------------------------------------
template<int H>
__global__ void softmax_kernel(const int* __restrict__ rowstart, const int* __restrict__ csr,
                               const float* __restrict__ logits, float* __restrict__ w) {
    int t = blockIdx.x * 256 + threadIdx.x;
    if (t >= NNODES * H) return;
    int n = t / H;
    int h = t - n * H;
    int s0 = rowstart[n], s1 = rowstart[n + 1];
    float lself = logits[(size_t)(NEDGES + n) * H + h];
    float mx = lself;
    for (int i = s0; i < s1; i++) {
        float l = logits[(size_t)csr[i] * H + h];
        mx = fmaxf(mx, l);
    }
    float den = 0.f;
    for (int i = s0; i < s1; i++) {
        float ex = (float)exp((double)__fsub_rn(logits[(size_t)csr[i] * H + h], mx));
        den = __fadd_rn(den, ex);
    }
    float exs = (float)exp((double)__fsub_rn(lself, mx));
    den = __fadd_rn(den, exs);
    for (int i = s0; i < s1; i++) {
        size_t idx = (size_t)csr[i] * H + h;
        float ex = (float)exp((double)__fsub_rn(logits[idx], mx));
        w[idx] = __fdiv_rn(ex, den);
    }
    w[(size_t)(NEDGES + n) * H + h] = __fdiv_rn(exs, den);
}

// ---------------------------------------------------------------------------
// Aggregation: out[n,c] = (Σ_e fp32(alpha_e * xl[src_e,c])) + bout[c]
// fp32 sequential, originals ascending then self LAST, no FMA contraction.
// ---------------------------------------------------------------------------
template<int H, bool RELU>
__global__ __launch_bounds__(256) void agg_kernel(
    const int* __restrict__ ei, const int* __restrict__ rowstart, const int* __restrict__ csr,
    const float* __restrict__ w, const float* __restrict__ xl,
    const float* __restrict__ bout, float* __restrict__ out) {
    int n = blockIdx.x;
    int c = threadIdx.x;
    int h = (H == 2) ? (c >> 7) : 0;
    float acc = 0.f;
    int s0 = rowstart[n], s1 = rowstart[n + 1];
    for (int i = s0; i < s1; i++) {
        int e = csr[i];
        int sn = ei[e];
        float p = __fmul_rn(w[(size_t)e * H + h], xl[(size_t)sn * F1DIM + c]);
        acc = __fadd_rn(acc, p);
    }
    float pself = __fmul_rn(w[(size_t)(NEDGES + n) * H + h], xl[(size_t)n * F1DIM + c]);
    acc = __fadd_rn(acc, pself);
    acc = __fadd_rn(acc, bout[c]);
    if (RELU) acc = fmaxf(acc, 0.f);
    out[(size_t)n * F1DIM + c] = acc;
}

// ---------------------------------------------------------------------------
// SAG scorer with XLA-tanh:
//   aggv[n] = Σ_{original e:dst=n} h2[src_e]
//   score = xla_tanhf( (aggv·Wrel + brel) + h2·Wroot )
// ---------------------------------------------------------------------------
__global__ __launch_bounds__(256) void aggvec_kernel(
    const int* __restrict__ ei, const int* __restrict__ rowstart, const int* __restrict__ csr,
    const float* __restrict__ h2, float* __restrict__ aggv) {
    int n = blockIdx.x;
    int c = threadIdx.x;
    float acc = 0.f;
    int s0 = rowstart[n], s1 = rowstart[n + 1];
    for (int i = s0; i < s1; i++) {
        int sn = ei[csr[i]];
        acc = __fadd_rn(acc, h2[(size_t)sn * F1DIM + c]);
    }
    aggv[(size_t)n * F1DIM + c] = acc;
}

__global__ __launch_bounds__(256) void score_dots_kernel(
    const float* __restrict__ h2, const float* __restrict__ aggv,
    const float* __restrict__ Wrel, const float* __restrict__ Wroot,
    const float* __restrict__ brel, float* __restrict__ score) {
    __shared__ float wr[256], wo[256];
    int t = threadIdx.x;
    wr[t] = Wrel[t];
    wo[t] = Wroot[t];
    __syncthreads();
    int n = blockIdx.x * 256 + t;
    const float* hv = h2 + (size_t)n * F1DIM;
    const float* av = aggv + (size_t)n * F1DIM;
    float s1 = 0.f, s2 = 0.f;
    for (int c = 0; c < F1DIM; c++) {
        s1 = fmaf(av[c], wr[c], s1);
        s2 = fmaf(hv[c], wo[c], s2);
    }
    float u = __fadd_rn(__fadd_rn(s1, brel[0]), s2);
    score[n] = xla_tanhf(u);   // XLA/Eigen tanh: saturates to +-1.0 at |u|>7.905
}

// ---------------------------------------------------------------------------
// Per-graph top-k (bitonic, fp32 score desc / index asc = lax.top_k stable)
// + head: xk[c] = fp32(h2[idx][c]*sv); z = seq-FMA(xk,Wlin)+blin; sigmoid.
// ---------------------------------------------------------------------------
__global__ __launch_bounds__(256) void topk_kernel(
    const float* __restrict__ score, const float* __restrict__ h2,
    const float* __restrict__ Wlin, const float* __restrict__ blin,
    float* __restrict__ out) {
    __shared__ float sv[256];
    __shared__ int si[256];
    __shared__ float wl[256];
    int t = threadIdx.x;
    int g = blockIdx.x;
    sv[t] = score[g * NGR + t];
    si[t] = t;
    wl[t] = Wlin[t];
    __syncthreads();
    for (int k = 2; k <= 256; k <<= 1) {
        for (int j = k >> 1; j > 0; j >>= 1) {
            int ixj = t ^ j;
            if (ixj > t) {
                float va = sv[t], vb = sv[ixj];
                int ia = si[t], ib = si[ixj];
                bool before = (va > vb) || (va == vb && ia < ib);  // stable: idx asc
                bool up = ((t & k) == 0);
                if (up ? !before : before) {
                    sv[t] = vb; sv[ixj] = va;
                    si[t] = ib; si[ixj] = ia;
                }
            }
            __syncthreads();
        }
    }
    if (t < KKEEP) {
        float v = sv[t];
        int idx = si[t];
        const float* hv = h2 + (size_t)(g * NGR + idx) * F1DIM;
        float acc = 0.f;
        for (int c = 0; c < F1DIM; c++) {
            float xc = __fmul_rn(hv[c], v);
            acc = fmaf(xc, wl[c], acc);
        }
        float z = __fadd_rn(acc, blin[0]);
        out[g * KKEEP + t] = (float)(1.0 / (1.0 + exp(-(double)z)));
    }
}

// ---------------------------------------------------------------------------
extern "C" void kernel_launch(void* const* d_in, const int* in_sizes, int n_in,
                              void* d_out, int out_size, void* d_ws, size_t ws_size,
                              hipStream_t stream) {
    const float* x        = (const float*)d_in[0];
    const int*   ei       = (const int*)d_in[1];
    const float* eattr    = (const float*)d_in[2];
    // d_in[3] = batch (unused; nodes are contiguous per graph)
    const float* Wl1  = (const float*)d_in[4];
    const float* bl1  = (const float*)d_in[5];
    const float* Wr1  = (const float*)d_in[6];
    const float* br1  = (const float*)d_in[7];
    const float* We1  = (const float*)d_in[8];
    const float* att1 = (const float*)d_in[9];
    const float* bout1= (const float*)d_in[10];
    const float* Wl2  = (const float*)d_in[11];
    const float* bl2  = (const float*)d_in[12];
    const float* Wr2  = (const float*)d_in[13];
    const float* br2  = (const float*)d_in[14];
    const float* We2  = (const float*)d_in[15];
    const float* att2 = (const float*)d_in[16];
    const float* bout2= (const float*)d_in[17];
    const float* Wrel = (const float*)d_in[18];
    const float* brel = (const float*)d_in[19];
    const float* Wroot= (const float*)d_in[20];
    const float* Wlin = (const float*)d_in[21];
    const float* blin = (const float*)d_in[22];
    float* out = (float*)d_out;

    // workspace carve
    char* p = (char*)d_ws;
    auto alloc = [&](size_t bytes) {
        void* r = (void*)p;
        p += (bytes + 255) & ~(size_t)255;
        return r;
    };
    int*   deg      = (int*)alloc(NNODES * 4);
    int*   rowstart = (int*)alloc((NNODES + 1) * 4);
    int*   fill     = (int*)alloc(NNODES * 4);
    int*   csr      = (int*)alloc(NEDGES * 4);
    float* loop_attr= (float*)alloc((size_t)NNODES * DEDGE * 4);
    float* bufA     = (float*)alloc((size_t)NNODES * F1DIM * 4);   // xl / aggv
    float* bufB     = (float*)alloc((size_t)NNODES * F1DIM * 4);   // xr
    float* bufC     = (float*)alloc((size_t)NNODES * F1DIM * 4);   // h1 then h2
    float* logitsB  = (float*)alloc((size_t)EATOT * 2 * 4);
    float* wB       = (float*)alloc((size_t)EATOT * 2 * 4);
    float* scoreV   = (float*)alloc(NNODES * 4);

    // CSR build (deterministic after sort)
    hipMemsetAsync(deg, 0, NNODES * 4, stream);
    count_kernel<<<NEDGES / 256, 256, 0, stream>>>(ei, deg);
    scan_kernel<<<1, 1024, 0, stream>>>(deg, rowstart, fill);
    scatter_kernel<<<NEDGES / 256, 256, 0, stream>>>(ei, fill, csr);
    sortcsr_kernel<<<NNODES / 256, 256, 0, stream>>>(rowstart, csr);
    loopattr_kernel<<<NNODES * DEDGE / 256, 256, 0, stream>>>(rowstart, csr, eattr, loop_attr);

    // ---- layer 1 (heads=2) ----
    gemm_lr_kernel<DNODE><<<NNODES / 16, 256, 0, stream>>>(x, Wl1, bl1, Wr1, br1, bufA, bufB);
    logits_kernel<2><<<2048, 256, 0, stream>>>(ei, eattr, loop_attr, bufA, bufB, We1, att1, logitsB);
    softmax_kernel<2><<<(NNODES * 2) / 256, 256, 0, stream>>>(rowstart, csr, logitsB, wB);
    agg_kernel<2, true><<<NNODES, 256, 0, stream>>>(ei, rowstart, csr, wB, bufA, bout1, bufC);

    // ---- layer 2 (heads=1) ----
    gemm_lr_kernel<F1DIM><<<NNODES / 16, 256, 0, stream>>>(bufC, Wl2, bl2, Wr2, br2, bufA, bufB);
    logits_kernel<1><<<2048, 256, 0, stream>>>(ei, eattr, loop_attr, bufA, bufB, We2, att2, logitsB);
    softmax_kernel<1><<<NNODES / 256, 256, 0, stream>>>(rowstart, csr, logitsB, wB);
    agg_kernel<1, false><<<NNODES, 256, 0, stream>>>(ei, rowstart, csr, wB, bufA, bout2, bufC);

    // ---- SAG pooling + head ----
    aggvec_kernel<<<NNODES, 256, 0, stream>>>(ei, rowstart, csr, bufC, bufA);
    score_dots_kernel<<<NNODES / 256, 256, 0, stream>>>(bufC, bufA, Wrel, Wroot, brel, scoreV);
    topk_kernel<<<NB, 256, 0, stream>>>(scoreV, bufC, Wlin, blin, out);
}

// Round 10
// 869.733 us; speedup vs baseline: 2.7821x; 1.5268x over previous
//
#include <hip/hip_runtime.h>
#include <math.h>

// Problem constants
#define NNODES   32768          // B*NG
#define NEDGES   262144         // B*EG
#define EATOT    (NEDGES + NNODES)  // edges + self loops = 294912
#define NB       128            // graphs
#define NGR      256            // nodes per graph
#define KKEEP    128            // top-k per graph
#define F1DIM    256
#define DNODE    64
#define DEDGE    32

// ---------------------------------------------------------------------------
// XLA/Eigen f32 tanh emulation: clamps to EXACTLY +-1.0 for |x| > 7.90531...
// Creates exact ties at 1.0 among saturated SAG scores; top_k breaks by index.
// DO NOT REPLACE with tanhf. DO NOT PERTURB upstream arithmetic: clamp
// membership is sensitive to ~1e-4 noise in u (round-8 lesson). All changes
// to upstream kernels must be bit-exact transformations.
// ---------------------------------------------------------------------------
__device__ __forceinline__ float xla_tanhf(float x) {
    float ax = fabsf(x);
    if (ax < 0.0004f) return x;
    if (ax > 7.90531110763549805f) return copysignf(1.0f, x);
    float x2 = __fmul_rn(x, x);
    float p = -2.76076847742355e-16f;
    p = fmaf(p, x2, 2.00018790482477e-13f);
    p = fmaf(p, x2, -8.60467152213735e-11f);
    p = fmaf(p, x2, 5.12229709037114e-08f);
    p = fmaf(p, x2, 1.48572235717979e-05f);
    p = fmaf(p, x2, 6.37261928875436e-04f);
    p = fmaf(p, x2, 4.89352455891786e-03f);
    p = __fmul_rn(x, p);
    float q = 1.19825839466702e-06f;
    q = fmaf(q, x2, 1.18534705686654e-04f);
    q = fmaf(q, x2, 2.26843463243900e-03f);
    q = fmaf(q, x2, 4.89352518554385e-03f);
    return __fdiv_rn(p, q);
}

// ---------------------------------------------------------------------------
// CSR build
// ---------------------------------------------------------------------------
__global__ void count_kernel(const int* __restrict__ ei, int* __restrict__ deg) {
    int t = blockIdx.x * 256 + threadIdx.x;
    if (t < NEDGES) atomicAdd(&deg[ei[NEDGES + t]], 1);
}

__global__ void scan_kernel(const int* __restrict__ deg, int* __restrict__ rowstart,
                            int* __restrict__ fill) {
    __shared__ int sh[1024];
    int t = threadIdx.x;
    int base = t * 32;
    int local[32];
    int s = 0;
#pragma unroll
    for (int i = 0; i < 32; i++) { local[i] = deg[base + i]; s += local[i]; }
    sh[t] = s;
    __syncthreads();
    for (int off = 1; off < 1024; off <<= 1) {
        int v = 0;
        if (t >= off) v = sh[t - off];
        __syncthreads();
        if (t >= off) sh[t] += v;
        __syncthreads();
    }
    int run = sh[t] - s;   // exclusive prefix
#pragma unroll
    for (int i = 0; i < 32; i++) {
        rowstart[base + i] = run;
        fill[base + i] = run;
        run += local[i];
    }
    if (t == 1023) rowstart[NNODES] = run;
}

__global__ void scatter_kernel(const int* __restrict__ ei, int* __restrict__ fill,
                               int* __restrict__ csr) {
    int t = blockIdx.x * 256 + threadIdx.x;
    if (t < NEDGES) {
        int d = ei[NEDGES + t];
        int slot = atomicAdd(&fill[d], 1);
        csr[slot] = t;
    }
}

// Sort each node's incoming-edge list ascending (np.add.at edge order).
__global__ void sortcsr_kernel(const int* __restrict__ rowstart, int* __restrict__ csr) {
    int n = blockIdx.x * 256 + threadIdx.x;
    if (n >= NNODES) return;
    int s0 = rowstart[n], s1 = rowstart[n + 1];
    for (int i = s0 + 1; i < s1; i++) {
        int v = csr[i];
        int j = i - 1;
        while (j >= s0 && csr[j] > v) { csr[j + 1] = csr[j]; j--; }
        csr[j + 1] = v;
    }
}

// loop_attr[n][c] = mean of incoming edge_attr — fp32 sequential in edge order
__global__ void loopattr_kernel(const int* __restrict__ rowstart, const int* __restrict__ csr,
                                const float* __restrict__ eattr, float* __restrict__ loop_attr) {
    int t = blockIdx.x * 256 + threadIdx.x;   // N*32 threads
    int n = t >> 5, c = t & 31;
    int s0 = rowstart[n], s1 = rowstart[n + 1];
    float sum = 0.f;
    for (int i = s0; i < s1; i++) sum = __fadd_rn(sum, eattr[(size_t)csr[i] * DEDGE + c]);
    float cnt = (float)(s1 - s0);
    loop_attr[t] = __fdiv_rn(sum, fmaxf(cnt, 1.f));
}

// ---------------------------------------------------------------------------
// Dense transforms: per output element, fp32 single accumulator, k ascending,
// fused FMA; bias added after. NPB=16 (bit-identical per-element math).
// ---------------------------------------------------------------------------
template<int KD>
__global__ __launch_bounds__(256) void gemm_lr_kernel(
    const float* __restrict__ X,
    const float* __restrict__ Wl, const float* __restrict__ bl,
    const float* __restrict__ Wr, const float* __restrict__ br,
    float* __restrict__ outL, float* __restrict__ outR) {
    constexpr int NPB = 16;
    __shared__ float xs[NPB * KD];
    int n0 = blockIdx.x * NPB;
    int c = threadIdx.x;
    for (int i = c; i < NPB * KD; i += 256) xs[i] = X[(size_t)n0 * KD + i];
    __syncthreads();
    float accL[NPB], accR[NPB];
#pragma unroll
    for (int m = 0; m < NPB; m++) { accL[m] = 0.f; accR[m] = 0.f; }
    for (int k = 0; k < KD; k++) {
        float wl = Wl[k * F1DIM + c];
        float wr = Wr[k * F1DIM + c];
#pragma unroll
        for (int m = 0; m < NPB; m++) {
            float xv = xs[m * KD + k];
            accL[m] = fmaf(xv, wl, accL[m]);
            accR[m] = fmaf(xv, wr, accR[m]);
        }
    }
    float blc = bl[c], brc = br[c];
#pragma unroll
    for (int m = 0; m < NPB; m++) {
        outL[(size_t)(n0 + m) * F1DIM + c] = __fadd_rn(accL[m], blc);
        outR[(size_t)(n0 + m) * F1DIM + c] = __fadd_rn(accR[m], brc);
    }
}

// ---------------------------------------------------------------------------
// Edge logits — BIT-EXACT to round-7/9 values, restructured for speed:
// 8-edge tiles per wave. Phase 1: pv per edge (identical arithmetic),
// staged to LDS (+4-float pad per edge row for bank spread). Phase 2:
// one lane per (edge, half, j) chain — exact serial __fadd_rn chains over
// L ascending, combined ((s0+s2)+(s1+s3)) via shfl_xor (fadd commutative,
// bit-exact). ea[] loads are wave-uniform -> scalar loads, no readlane.
// ---------------------------------------------------------------------------
template<int H>
__global__ __launch_bounds__(256) void logits_kernel(
    const int* __restrict__ ei,
    const float* __restrict__ eattr, const float* __restrict__ loop_attr,
    const float* __restrict__ xl, const float* __restrict__ xr,
    const float* __restrict__ We, const float* __restrict__ att,
    float* __restrict__ logits) {
    constexpr int TILE = 8;
    constexpr int EPAD = 260;                 // 256 + 4 pad floats per edge
    __shared__ float stageF[4][TILE * EPAD];  // 33280 B
    int t = threadIdx.x;
    int lane = t & 63;
    int wv = t >> 6;

    // We -> registers: wreg[k] = We[k][lane*4 .. lane*4+3]
    float4 wreg[DEDGE];
#pragma unroll
    for (int k = 0; k < DEDGE; k++) wreg[k] = ((const float4*)We)[k * 64 + lane];
    float4 a4 = ((const float4*)att)[lane];

    int wid = (blockIdx.x * 256 + t) >> 6;
    int nw = (gridDim.x * 256) >> 6;
    int ntiles = EATOT / TILE;

    for (int tile = wid; tile < ntiles; tile += nw) {
        int ebase = __builtin_amdgcn_readfirstlane(tile) * TILE;

        // ---- phase 1: compute pv for TILE edges, stage to LDS ----
        for (int ee = 0; ee < TILE; ee++) {
            int e = ebase + ee;
            int s, d;
            const float* ea;
            if (e < NEDGES) {
                s = ei[e]; d = ei[NEDGES + e];
                ea = eattr + (size_t)e * DEDGE;
            } else {
                s = e - NEDGES; d = s;
                ea = loop_attr + (size_t)(e - NEDGES) * DEDGE;
            }
            s = __builtin_amdgcn_readfirstlane(s);
            d = __builtin_amdgcn_readfirstlane(d);
            float ef0 = 0.f, ef1 = 0.f, ef2 = 0.f, ef3 = 0.f;
#pragma unroll
            for (int k = 0; k < DEDGE; k++) {
                float eak = ea[k];   // wave-uniform address -> scalar load
                ef0 = fmaf(eak, wreg[k].x, ef0);
                ef1 = fmaf(eak, wreg[k].y, ef1);
                ef2 = fmaf(eak, wreg[k].z, ef2);
                ef3 = fmaf(eak, wreg[k].w, ef3);
            }
            float4 l4 = ((const float4*)(xl + (size_t)s * F1DIM))[lane];
            float4 r4 = ((const float4*)(xr + (size_t)d * F1DIM))[lane];
            float mv, lk;
            float4 pv;
            mv = __fadd_rn(__fadd_rn(l4.x, r4.x), ef0);
            lk = mv > 0.f ? mv : __fmul_rn(0.2f, mv);
            pv.x = __fmul_rn(lk, a4.x);
            mv = __fadd_rn(__fadd_rn(l4.y, r4.y), ef1);
            lk = mv > 0.f ? mv : __fmul_rn(0.2f, mv);
            pv.y = __fmul_rn(lk, a4.y);
            mv = __fadd_rn(__fadd_rn(l4.z, r4.z), ef2);
            lk = mv > 0.f ? mv : __fmul_rn(0.2f, mv);
            pv.z = __fmul_rn(lk, a4.z);
            mv = __fadd_rn(__fadd_rn(l4.w, r4.w), ef3);
            lk = mv > 0.f ? mv : __fmul_rn(0.2f, mv);
            pv.w = __fmul_rn(lk, a4.w);
            // ee*EPAD*4B = ee*1040 B, 1040 % 16 == 0 -> 16B-aligned float4 store
            *(float4*)&stageF[wv][ee * EPAD + lane * 4] = pv;
        }

        // ---- phase 2: lane-parallel exact serial chains ----
        if (H == 2) {
            int edge = lane >> 3;        // 0..7
            int half = (lane >> 2) & 1;  // 0 = head0 (c 0..127), 1 = head1
            int j = lane & 3;
            const float* base = &stageF[wv][edge * EPAD + half * 128 + j];
            float s = 0.f;
#pragma unroll
            for (int L = 0; L < 32; L++)
                s = __fadd_rn(s, base[L * 4]);
            float o = __fadd_rn(s, __shfl_xor(s, 2));
            float r = __fadd_rn(o, __shfl_xor(o, 1));
            if (j == 0) logits[(size_t)(ebase + edge) * 2 + half] = r;
        } else {
            float s = 0.f;
            if (lane < 32) {
                int edge = lane >> 2;    // 0..7
                int j = lane & 3;
                const float* base = &stageF[wv][edge * EPAD + j];
#pragma unroll
                for (int L = 0; L < 64; L++)
                    s = __fadd_rn(s, base[L * 4]);
                float o = __fadd_rn(s, __shfl_xor(s, 2));
                float r = __fadd_rn(o, __shfl_xor(o, 1));
                if ((lane & 3) == 0) logits[ebase + (lane >> 2)] = r;
            }
        }
    }
}

// ---------------------------------------------------------------------------
// Segment softmax per (node, head), fp32, edge order: originals ascending,
// self-loop LAST. exp correctly rounded via double.
// ---------------------------------------------------------------------------
template<int H>
__global__ void softmax_kernel(const int* __restrict__ rowstart, const int* __restrict__ csr,
                               const float* __restrict__ logits, float* __restrict__ w) {
    int t = blockIdx.x * 256 + threadIdx.x;
    if (t >= NNODES * H) return;
    int n = t / H;
    int h = t - n * H;
    int s0 = rowstart[n], s1 = rowstart[n + 1];
    float lself = logits[(size_t)(NEDGES + n) * H + h];
    float mx = lself;
    for (int i = s0; i < s1; i++) {
        float l = logits[(size_t)csr[i] * H + h];
        mx = fmaxf(mx, l);
    }
    float den = 0.f;
    for (int i = s0; i < s1; i++) {
        float ex = (float)exp((double)__fsub_rn(logits[(size_t)csr[i] * H + h], mx));
        den = __fadd_rn(den, ex);
    }
    float exs = (float)exp((double)__fsub_rn(lself, mx));
    den = __fadd_rn(den, exs);
    for (int i = s0; i < s1; i++) {
        size_t idx = (size_t)csr[i] * H + h;
        float ex = (float)exp((double)__fsub_rn(logits[idx], mx));
        w[idx] = __fdiv_rn(ex, den);
    }
    w[(size_t)(NEDGES + n) * H + h] = __fdiv_rn(exs, den);
}

// ---------------------------------------------------------------------------
// Aggregation: out[n,c] = (Σ_e fp32(alpha_e * xl[src_e,c])) + bout[c]
// fp32 sequential, originals ascending then self LAST, no FMA contraction.
// ---------------------------------------------------------------------------
template<int H, bool RELU>
__global__ __launch_bounds__(256) void agg_kernel(
    const int* __restrict__ ei, const int* __restrict__ rowstart, const int* __restrict__ csr,
    const float* __restrict__ w, const float* __restrict__ xl,
    const float* __restrict__ bout, float* __restrict__ out) {
    int n = blockIdx.x;
    int c = threadIdx.x;
    int h = (H == 2) ? (c >> 7) : 0;
    float acc = 0.f;
    int s0 = rowstart[n], s1 = rowstart[n + 1];
    for (int i = s0; i < s1; i++) {
        int e = csr[i];
        int sn = ei[e];
        float p = __fmul_rn(w[(size_t)e * H + h], xl[(size_t)sn * F1DIM + c]);
        acc = __fadd_rn(acc, p);
    }
    float pself = __fmul_rn(w[(size_t)(NEDGES + n) * H + h], xl[(size_t)n * F1DIM + c]);
    acc = __fadd_rn(acc, pself);
    acc = __fadd_rn(acc, bout[c]);
    if (RELU) acc = fmaxf(acc, 0.f);
    out[(size_t)n * F1DIM + c] = acc;
}

// ---------------------------------------------------------------------------
// SAG scorer with XLA-tanh:
//   aggv[n] = Σ_{original e:dst=n} h2[src_e]
//   score = xla_tanhf( (aggv·Wrel + brel) + h2·Wroot )
// ---------------------------------------------------------------------------
__global__ __launch_bounds__(256) void aggvec_kernel(
    const int* __restrict__ ei, const int* __restrict__ rowstart, const int* __restrict__ csr,
    const float* __restrict__ h2, float* __restrict__ aggv) {
    int n = blockIdx.x;
    int c = threadIdx.x;
    float acc = 0.f;
    int s0 = rowstart[n], s1 = rowstart[n + 1];
    for (int i = s0; i < s1; i++) {
        int sn = ei[csr[i]];
        acc = __fadd_rn(acc, h2[(size_t)sn * F1DIM + c]);
    }
    aggv[(size_t)n * F1DIM + c] = acc;
}

__global__ __launch_bounds__(256) void score_dots_kernel(
    const float* __restrict__ h2, const float* __restrict__ aggv,
    const float* __restrict__ Wrel, const float* __restrict__ Wroot,
    const float* __restrict__ brel, float* __restrict__ score) {
    __shared__ float wr[256], wo[256];
    int t = threadIdx.x;
    wr[t] = Wrel[t];
    wo[t] = Wroot[t];
    __syncthreads();
    int n = blockIdx.x * 256 + t;
    const float* hv = h2 + (size_t)n * F1DIM;
    const float* av = aggv + (size_t)n * F1DIM;
    float s1 = 0.f, s2 = 0.f;
    for (int c = 0; c < F1DIM; c++) {
        s1 = fmaf(av[c], wr[c], s1);
        s2 = fmaf(hv[c], wo[c], s2);
    }
    float u = __fadd_rn(__fadd_rn(s1, brel[0]), s2);
    score[n] = xla_tanhf(u);   // XLA/Eigen tanh: saturates to +-1.0 at |u|>7.905
}

// ---------------------------------------------------------------------------
// Per-graph top-k (bitonic, fp32 score desc / index asc = lax.top_k stable)
// + head: xk[c] = fp32(h2[idx][c]*sv); z = seq-FMA(xk,Wlin)+blin; sigmoid.
// ---------------------------------------------------------------------------
__global__ __launch_bounds__(256) void topk_kernel(
    const float* __restrict__ score, const float* __restrict__ h2,
    const float* __restrict__ Wlin, const float* __restrict__ blin,
    float* __restrict__ out) {
    __shared__ float sv[256];
    __shared__ int si[256];
    __shared__ float wl[256];
    int t = threadIdx.x;
    int g = blockIdx.x;
    sv[t] = score[g * NGR + t];
    si[t] = t;
    wl[t] = Wlin[t];
    __syncthreads();
    for (int k = 2; k <= 256; k <<= 1) {
        for (int j = k >> 1; j > 0; j >>= 1) {
            int ixj = t ^ j;
            if (ixj > t) {
                float va = sv[t], vb = sv[ixj];
                int ia = si[t], ib = si[ixj];
                bool before = (va > vb) || (va == vb && ia < ib);  // stable: idx asc
                bool up = ((t & k) == 0);
                if (up ? !before : before) {
                    sv[t] = vb; sv[ixj] = va;
                    si[t] = ib; si[ixj] = ia;
                }
            }
            __syncthreads();
        }
    }
    if (t < KKEEP) {
        float v = sv[t];
        int idx = si[t];
        const float* hv = h2 + (size_t)(g * NGR + idx) * F1DIM;
        float acc = 0.f;
        for (int c = 0; c < F1DIM; c++) {
            float xc = __fmul_rn(hv[c], v);
            acc = fmaf(xc, wl[c], acc);
        }
        float z = __fadd_rn(acc, blin[0]);
        out[g * KKEEP + t] = (float)(1.0 / (1.0 + exp(-(double)z)));
    }
}

// ---------------------------------------------------------------------------
extern "C" void kernel_launch(void* const* d_in, const int* in_sizes, int n_in,
                              void* d_out, int out_size, void* d_ws, size_t ws_size,
                              hipStream_t stream) {
    const float* x        = (const float*)d_in[0];
    const int*   ei       = (const int*)d_in[1];
    const float* eattr    = (const float*)d_in[2];
    // d_in[3] = batch (unused; nodes are contiguous per graph)
    const float* Wl1  = (const float*)d_in[4];
    const float* bl1  = (const float*)d_in[5];
    const float* Wr1  = (const float*)d_in[6];
    const float* br1  = (const float*)d_in[7];
    const float* We1  = (const float*)d_in[8];
    const float* att1 = (const float*)d_in[9];
    const float* bout1= (const float*)d_in[10];
    const float* Wl2  = (const float*)d_in[11];
    const float* bl2  = (const float*)d_in[12];
    const float* Wr2  = (const float*)d_in[13];
    const float* br2  = (const float*)d_in[14];
    const float* We2  = (const float*)d_in[15];
    const float* att2 = (const float*)d_in[16];
    const float* bout2= (const float*)d_in[17];
    const float* Wrel = (const float*)d_in[18];
    const float* brel = (const float*)d_in[19];
    const float* Wroot= (const float*)d_in[20];
    const float* Wlin = (const float*)d_in[21];
    const float* blin = (const float*)d_in[22];
    float* out = (float*)d_out;

    // workspace carve
    char* p = (char*)d_ws;
    auto alloc = [&](size_t bytes) {
        void* r = (void*)p;
        p += (bytes + 255) & ~(size_t)255;
        return r;
    };
    int*   deg      = (int*)alloc(NNODES * 4);
    int*   rowstart = (int*)alloc((NNODES + 1) * 4);
    int*   fill     = (int*)alloc(NNODES * 4);
    int*   csr      = (int*)alloc(NEDGES * 4);
    float* loop_attr= (float*)alloc((size_t)NNODES * DEDGE * 4);
    float* bufA     = (float*)alloc((size_t)NNODES * F1DIM * 4);   // xl / aggv
    float* bufB     = (float*)alloc((size_t)NNODES * F1DIM * 4);   // xr
    float* bufC     = (float*)alloc((size_t)NNODES * F1DIM * 4);   // h1 then h2
    float* logitsB  = (float*)alloc((size_t)EATOT * 2 * 4);
    float* wB       = (float*)alloc((size_t)EATOT * 2 * 4);
    float* scoreV   = (float*)alloc(NNODES * 4);

    // CSR build (deterministic after sort)
    hipMemsetAsync(deg, 0, NNODES * 4, stream);
    count_kernel<<<NEDGES / 256, 256, 0, stream>>>(ei, deg);
    scan_kernel<<<1, 1024, 0, stream>>>(deg, rowstart, fill);
    scatter_kernel<<<NEDGES / 256, 256, 0, stream>>>(ei, fill, csr);
    sortcsr_kernel<<<NNODES / 256, 256, 0, stream>>>(rowstart, csr);
    loopattr_kernel<<<NNODES * DEDGE / 256, 256, 0, stream>>>(rowstart, csr, eattr, loop_attr);

    // ---- layer 1 (heads=2) ----
    gemm_lr_kernel<DNODE><<<NNODES / 16, 256, 0, stream>>>(x, Wl1, bl1, Wr1, br1, bufA, bufB);
    logits_kernel<2><<<2048, 256, 0, stream>>>(ei, eattr, loop_attr, bufA, bufB, We1, att1, logitsB);
    softmax_kernel<2><<<(NNODES * 2) / 256, 256, 0, stream>>>(rowstart, csr, logitsB, wB);
    agg_kernel<2, true><<<NNODES, 256, 0, stream>>>(ei, rowstart, csr, wB, bufA, bout1, bufC);

    // ---- layer 2 (heads=1) ----
    gemm_lr_kernel<F1DIM><<<NNODES / 16, 256, 0, stream>>>(bufC, Wl2, bl2, Wr2, br2, bufA, bufB);
    logits_kernel<1><<<2048, 256, 0, stream>>>(ei, eattr, loop_attr, bufA, bufB, We2, att2, logitsB);
    softmax_kernel<1><<<NNODES / 256, 256, 0, stream>>>(rowstart, csr, logitsB, wB);
    agg_kernel<1, false><<<NNODES, 256, 0, stream>>>(ei, rowstart, csr, wB, bufA, bout2, bufC);

    // ---- SAG pooling + head ----
    aggvec_kernel<<<NNODES, 256, 0, stream>>>(ei, rowstart, csr, bufC, bufA);
    score_dots_kernel<<<NNODES / 256, 256, 0, stream>>>(bufC, bufA, Wrel, Wroot, brel, scoreV);
    topk_kernel<<<NB, 256, 0, stream>>>(scoreV, bufC, Wlin, blin, out);
}

// Round 11
// 830.961 us; speedup vs baseline: 2.9119x; 1.0467x over previous
//
#include <hip/hip_runtime.h>
#include <math.h>

// Problem constants
#define NNODES   32768          // B*NG
#define NEDGES   262144         // B*EG
#define EATOT    (NEDGES + NNODES)  // edges + self loops = 294912
#define NB       128            // graphs
#define NGR      256            // nodes per graph
#define KKEEP    128            // top-k per graph
#define F1DIM    256
#define DNODE    64
#define DEDGE    32

// ---------------------------------------------------------------------------
// XLA/Eigen f32 tanh emulation: clamps to EXACTLY +-1.0 for |x| > 7.90531...
// Creates exact ties at 1.0 among saturated SAG scores; top_k breaks by index.
// DO NOT REPLACE with tanhf. DO NOT PERTURB upstream arithmetic: clamp
// membership is sensitive to ~1e-4 noise in u (round-8 lesson). All changes
// to upstream kernels must be bit-exact transformations.
// ---------------------------------------------------------------------------
__device__ __forceinline__ float xla_tanhf(float x) {
    float ax = fabsf(x);
    if (ax < 0.0004f) return x;
    if (ax > 7.90531110763549805f) return copysignf(1.0f, x);
    float x2 = __fmul_rn(x, x);
    float p = -2.76076847742355e-16f;
    p = fmaf(p, x2, 2.00018790482477e-13f);
    p = fmaf(p, x2, -8.60467152213735e-11f);
    p = fmaf(p, x2, 5.12229709037114e-08f);
    p = fmaf(p, x2, 1.48572235717979e-05f);
    p = fmaf(p, x2, 6.37261928875436e-04f);
    p = fmaf(p, x2, 4.89352455891786e-03f);
    p = __fmul_rn(x, p);
    float q = 1.19825839466702e-06f;
    q = fmaf(q, x2, 1.18534705686654e-04f);
    q = fmaf(q, x2, 2.26843463243900e-03f);
    q = fmaf(q, x2, 4.89352518554385e-03f);
    return __fdiv_rn(p, q);
}

// ---------------------------------------------------------------------------
// CSR build
// ---------------------------------------------------------------------------
__global__ void count_kernel(const int* __restrict__ ei, int* __restrict__ deg) {
    int t = blockIdx.x * 256 + threadIdx.x;
    if (t < NEDGES) atomicAdd(&deg[ei[NEDGES + t]], 1);
}

__global__ void scan_kernel(const int* __restrict__ deg, int* __restrict__ rowstart,
                            int* __restrict__ fill) {
    __shared__ int sh[1024];
    int t = threadIdx.x;
    int base = t * 32;
    int local[32];
    int s = 0;
#pragma unroll
    for (int i = 0; i < 32; i++) { local[i] = deg[base + i]; s += local[i]; }
    sh[t] = s;
    __syncthreads();
    for (int off = 1; off < 1024; off <<= 1) {
        int v = 0;
        if (t >= off) v = sh[t - off];
        __syncthreads();
        if (t >= off) sh[t] += v;
        __syncthreads();
    }
    int run = sh[t] - s;   // exclusive prefix
#pragma unroll
    for (int i = 0; i < 32; i++) {
        rowstart[base + i] = run;
        fill[base + i] = run;
        run += local[i];
    }
    if (t == 1023) rowstart[NNODES] = run;
}

__global__ void scatter_kernel(const int* __restrict__ ei, int* __restrict__ fill,
                               int* __restrict__ csr) {
    int t = blockIdx.x * 256 + threadIdx.x;
    if (t < NEDGES) {
        int d = ei[NEDGES + t];
        int slot = atomicAdd(&fill[d], 1);
        csr[slot] = t;
    }
}

// Sort each node's incoming-edge list ascending (np.add.at edge order).
__global__ void sortcsr_kernel(const int* __restrict__ rowstart, int* __restrict__ csr) {
    int n = blockIdx.x * 256 + threadIdx.x;
    if (n >= NNODES) return;
    int s0 = rowstart[n], s1 = rowstart[n + 1];
    for (int i = s0 + 1; i < s1; i++) {
        int v = csr[i];
        int j = i - 1;
        while (j >= s0 && csr[j] > v) { csr[j + 1] = csr[j]; j--; }
        csr[j + 1] = v;
    }
}

// loop_attr[n][c] = mean of incoming edge_attr — fp32 sequential in edge order
__global__ void loopattr_kernel(const int* __restrict__ rowstart, const int* __restrict__ csr,
                                const float* __restrict__ eattr, float* __restrict__ loop_attr) {
    int t = blockIdx.x * 256 + threadIdx.x;   // N*32 threads
    int n = t >> 5, c = t & 31;
    int s0 = rowstart[n], s1 = rowstart[n + 1];
    float sum = 0.f;
    for (int i = s0; i < s1; i++) sum = __fadd_rn(sum, eattr[(size_t)csr[i] * DEDGE + c]);
    float cnt = (float)(s1 - s0);
    loop_attr[t] = __fdiv_rn(sum, fmaxf(cnt, 1.f));
}

// ---------------------------------------------------------------------------
// Dense transforms: per output element, fp32 single accumulator, k ascending,
// fused FMA; bias added after. NPB=16. Stage buffer TRANSPOSED to [KD][NPB]
// so the 16 m-values per k are contiguous -> 4 ds_read_b128 per k instead of
// 16 ds_read_b32 (memory layout change only; accumulation order bit-exact).
// ---------------------------------------------------------------------------
template<int KD>
__global__ __launch_bounds__(256) void gemm_lr_kernel(
    const float* __restrict__ X,
    const float* __restrict__ Wl, const float* __restrict__ bl,
    const float* __restrict__ Wr, const float* __restrict__ br,
    float* __restrict__ outL, float* __restrict__ outR) {
    constexpr int NPB = 16;
    __shared__ float xs[KD * NPB];   // xs[k][m]
    int n0 = blockIdx.x * NPB;
    int c = threadIdx.x;
    for (int i = c; i < NPB * KD; i += 256) {
        int m = i / KD, k = i - m * KD;
        xs[k * NPB + m] = X[(size_t)n0 * KD + i];
    }
    __syncthreads();
    float accL[NPB], accR[NPB];
#pragma unroll
    for (int m = 0; m < NPB; m++) { accL[m] = 0.f; accR[m] = 0.f; }
    for (int k = 0; k < KD; k++) {
        float wl = Wl[k * F1DIM + c];
        float wr = Wr[k * F1DIM + c];
        float4 xv0 = *(const float4*)&xs[k * NPB + 0];
        float4 xv1 = *(const float4*)&xs[k * NPB + 4];
        float4 xv2 = *(const float4*)&xs[k * NPB + 8];
        float4 xv3 = *(const float4*)&xs[k * NPB + 12];
        float xv[NPB] = { xv0.x, xv0.y, xv0.z, xv0.w, xv1.x, xv1.y, xv1.z, xv1.w,
                          xv2.x, xv2.y, xv2.z, xv2.w, xv3.x, xv3.y, xv3.z, xv3.w };
#pragma unroll
        for (int m = 0; m < NPB; m++) {
            accL[m] = fmaf(xv[m], wl, accL[m]);
            accR[m] = fmaf(xv[m], wr, accR[m]);
        }
    }
    float blc = bl[c], brc = br[c];
#pragma unroll
    for (int m = 0; m < NPB; m++) {
        outL[(size_t)(n0 + m) * F1DIM + c] = __fadd_rn(accL[m], blc);
        outR[(size_t)(n0 + m) * F1DIM + c] = __fadd_rn(accR[m], brc);
    }
}

// ---------------------------------------------------------------------------
// Edge logits — BIT-EXACT to round-7/9 values, restructured for speed:
// 8-edge tiles per wave. Phase 1: pv per edge (identical arithmetic),
// staged to LDS (+4-float pad per edge row for bank spread). Phase 2:
// one lane per (edge, half, j) chain — exact serial __fadd_rn chains over
// L ascending, combined ((s0+s2)+(s1+s3)) via shfl_xor (fadd commutative,
// bit-exact). ea[] loads are wave-uniform -> scalar loads, no readlane.
// ---------------------------------------------------------------------------
template<int H>
__global__ __launch_bounds__(256) void logits_kernel(
    const int* __restrict__ ei,
    const float* __restrict__ eattr, const float* __restrict__ loop_attr,
    const float* __restrict__ xl, const float* __restrict__ xr,
    const float* __restrict__ We, const float* __restrict__ att,
    float* __restrict__ logits) {
    constexpr int TILE = 8;
    constexpr int EPAD = 260;                 // 256 + 4 pad floats per edge
    __shared__ float stageF[4][TILE * EPAD];  // 33280 B
    int t = threadIdx.x;
    int lane = t & 63;
    int wv = t >> 6;

    // We -> registers: wreg[k] = We[k][lane*4 .. lane*4+3]
    float4 wreg[DEDGE];
#pragma unroll
    for (int k = 0; k < DEDGE; k++) wreg[k] = ((const float4*)We)[k * 64 + lane];
    float4 a4 = ((const float4*)att)[lane];

    int wid = (blockIdx.x * 256 + t) >> 6;
    int nw = (gridDim.x * 256) >> 6;
    int ntiles = EATOT / TILE;

    for (int tile = wid; tile < ntiles; tile += nw) {
        int ebase = __builtin_amdgcn_readfirstlane(tile) * TILE;

        // ---- phase 1: compute pv for TILE edges, stage to LDS ----
        for (int ee = 0; ee < TILE; ee++) {
            int e = ebase + ee;
            int s, d;
            const float* ea;
            if (e < NEDGES) {
                s = ei[e]; d = ei[NEDGES + e];
                ea = eattr + (size_t)e * DEDGE;
            } else {
                s = e - NEDGES; d = s;
                ea = loop_attr + (size_t)(e - NEDGES) * DEDGE;
            }
            s = __builtin_amdgcn_readfirstlane(s);
            d = __builtin_amdgcn_readfirstlane(d);
            float ef0 = 0.f, ef1 = 0.f, ef2 = 0.f, ef3 = 0.f;
#pragma unroll
            for (int k = 0; k < DEDGE; k++) {
                float eak = ea[k];   // wave-uniform address -> scalar load
                ef0 = fmaf(eak, wreg[k].x, ef0);
                ef1 = fmaf(eak, wreg[k].y, ef1);
                ef2 = fmaf(eak, wreg[k].z, ef2);
                ef3 = fmaf(eak, wreg[k].w, ef3);
            }
            float4 l4 = ((const float4*)(xl + (size_t)s * F1DIM))[lane];
            float4 r4 = ((const float4*)(xr + (size_t)d * F1DIM))[lane];
            float mv, lk;
            float4 pv;
            mv = __fadd_rn(__fadd_rn(l4.x, r4.x), ef0);
            lk = mv > 0.f ? mv : __fmul_rn(0.2f, mv);
            pv.x = __fmul_rn(lk, a4.x);
            mv = __fadd_rn(__fadd_rn(l4.y, r4.y), ef1);
            lk = mv > 0.f ? mv : __fmul_rn(0.2f, mv);
            pv.y = __fmul_rn(lk, a4.y);
            mv = __fadd_rn(__fadd_rn(l4.z, r4.z), ef2);
            lk = mv > 0.f ? mv : __fmul_rn(0.2f, mv);
            pv.z = __fmul_rn(lk, a4.z);
            mv = __fadd_rn(__fadd_rn(l4.w, r4.w), ef3);
            lk = mv > 0.f ? mv : __fmul_rn(0.2f, mv);
            pv.w = __fmul_rn(lk, a4.w);
            // ee*EPAD*4B = ee*1040 B, 1040 % 16 == 0 -> 16B-aligned float4 store
            *(float4*)&stageF[wv][ee * EPAD + lane * 4] = pv;
        }

        // ---- phase 2: lane-parallel exact serial chains ----
        if (H == 2) {
            int edge = lane >> 3;        // 0..7
            int half = (lane >> 2) & 1;  // 0 = head0 (c 0..127), 1 = head1
            int j = lane & 3;
            const float* base = &stageF[wv][edge * EPAD + half * 128 + j];
            float s = 0.f;
#pragma unroll
            for (int L = 0; L < 32; L++)
                s = __fadd_rn(s, base[L * 4]);
            float o = __fadd_rn(s, __shfl_xor(s, 2));
            float r = __fadd_rn(o, __shfl_xor(o, 1));
            if (j == 0) logits[(size_t)(ebase + edge) * 2 + half] = r;
        } else {
            float s = 0.f;
            if (lane < 32) {
                int edge = lane >> 2;    // 0..7
                int j = lane & 3;
                const float* base = &stageF[wv][edge * EPAD + j];
#pragma unroll
                for (int L = 0; L < 64; L++)
                    s = __fadd_rn(s, base[L * 4]);
                float o = __fadd_rn(s, __shfl_xor(s, 2));
                float r = __fadd_rn(o, __shfl_xor(o, 1));
                if ((lane & 3) == 0) logits[ebase + (lane >> 2)] = r;
            }
        }
    }
}

// ---------------------------------------------------------------------------
// Segment softmax per (node, head), fp32, edge order: originals ascending,
// self-loop LAST. exp correctly rounded via double.
// ---------------------------------------------------------------------------
template<int H>
__global__ void softmax_kernel(const int* __restrict__ rowstart, const int* __restrict__ csr,
                               const float* __restrict__ logits, float* __restrict__ w) {
    int t = blockIdx.x * 256 + threadIdx.x;
    if (t >= NNODES * H) return;
    int n = t / H;
    int h = t - n * H;
    int s0 = rowstart[n], s1 = rowstart[n + 1];
    float lself = logits[(size_t)(NEDGES + n) * H + h];
    float mx = lself;
    for (int i = s0; i < s1; i++) {
        float l = logits[(size_t)csr[i] * H + h];
        mx = fmaxf(mx, l);
    }
    float den = 0.f;
    for (int i = s0; i < s1; i++) {
        float ex = (float)exp((double)__fsub_rn(logits[(size_t)csr[i] * H + h], mx));
        den = __fadd_rn(den, ex);
    }
    float exs = (float)exp((double)__fsub_rn(lself, mx));
    den = __fadd_rn(den, exs);
    for (int i = s0; i < s1; i++) {
        size_t idx = (size_t)csr[i] * H + h;
        float ex = (float)exp((double)__fsub_rn(logits[idx], mx));
        w[idx] = __fdiv_rn(ex, den);
    }
    w[(size_t)(NEDGES + n) * H + h] = __fdiv_rn(exs, den);
}

// ---------------------------------------------------------------------------
// Aggregation: out[n,c] = (Σ_e fp32(alpha_e * xl[src_e,c])) + bout[c]
// fp32 sequential, originals ascending then self LAST, no FMA contraction.
// ---------------------------------------------------------------------------
template<int H, bool RELU>
__global__ __launch_bounds__(256) void agg_kernel(
    const int* __restrict__ ei, const int* __restrict__ rowstart, const int* __restrict__ csr,
    const float* __restrict__ w, const float* __restrict__ xl,
    const float* __restrict__ bout, float* __restrict__ out) {
    int n = blockIdx.x;
    int c = threadIdx.x;
    int h = (H == 2) ? (c >> 7) : 0;
    float acc = 0.f;
    int s0 = rowstart[n], s1 = rowstart[n + 1];
    for (int i = s0; i < s1; i++) {
        int e = csr[i];
        int sn = ei[e];
        float p = __fmul_rn(w[(size_t)e * H + h], xl[(size_t)sn * F1DIM + c]);
        acc = __fadd_rn(acc, p);
    }
    float pself = __fmul_rn(w[(size_t)(NEDGES + n) * H + h], xl[(size_t)n * F1DIM + c]);
    acc = __fadd_rn(acc, pself);
    acc = __fadd_rn(acc, bout[c]);
    if (RELU) acc = fmaxf(acc, 0.f);
    out[(size_t)n * F1DIM + c] = acc;
}

// ---------------------------------------------------------------------------
// SAG scorer with XLA-tanh:
//   aggv[n] = Σ_{original e:dst=n} h2[src_e]
//   score = xla_tanhf( (aggv·Wrel + brel) + h2·Wroot )
// ---------------------------------------------------------------------------
__global__ __launch_bounds__(256) void aggvec_kernel(
    const int* __restrict__ ei, const int* __restrict__ rowstart, const int* __restrict__ csr,
    const float* __restrict__ h2, float* __restrict__ aggv) {
    int n = blockIdx.x;
    int c = threadIdx.x;
    float acc = 0.f;
    int s0 = rowstart[n], s1 = rowstart[n + 1];
    for (int i = s0; i < s1; i++) {
        int sn = ei[csr[i]];
        acc = __fadd_rn(acc, h2[(size_t)sn * F1DIM + c]);
    }
    aggv[(size_t)n * F1DIM + c] = acc;
}

__global__ __launch_bounds__(256) void score_dots_kernel(
    const float* __restrict__ h2, const float* __restrict__ aggv,
    const float* __restrict__ Wrel, const float* __restrict__ Wroot,
    const float* __restrict__ brel, float* __restrict__ score) {
    __shared__ float wr[256], wo[256];
    int t = threadIdx.x;
    wr[t] = Wrel[t];
    wo[t] = Wroot[t];
    __syncthreads();
    int n = blockIdx.x * 256 + t;
    const float* hv = h2 + (size_t)n * F1DIM;
    const float* av = aggv + (size_t)n * F1DIM;
    float s1 = 0.f, s2 = 0.f;
    for (int c = 0; c < F1DIM; c++) {
        s1 = fmaf(av[c], wr[c], s1);
        s2 = fmaf(hv[c], wo[c], s2);
    }
    float u = __fadd_rn(__fadd_rn(s1, brel[0]), s2);
    score[n] = xla_tanhf(u);   // XLA/Eigen tanh: saturates to +-1.0 at |u|>7.905
}

// ---------------------------------------------------------------------------
// Per-graph top-k (bitonic, fp32 score desc / index asc = lax.top_k stable)
// + head: xk[c] = fp32(h2[idx][c]*sv); z = seq-FMA(xk,Wlin)+blin; sigmoid.
// ---------------------------------------------------------------------------
__global__ __launch_bounds__(256) void topk_kernel(
    const float* __restrict__ score, const float* __restrict__ h2,
    const float* __restrict__ Wlin, const float* __restrict__ blin,
    float* __restrict__ out) {
    __shared__ float sv[256];
    __shared__ int si[256];
    __shared__ float wl[256];
    int t = threadIdx.x;
    int g = blockIdx.x;
    sv[t] = score[g * NGR + t];
    si[t] = t;
    wl[t] = Wlin[t];
    __syncthreads();
    for (int k = 2; k <= 256; k <<= 1) {
        for (int j = k >> 1; j > 0; j >>= 1) {
            int ixj = t ^ j;
            if (ixj > t) {
                float va = sv[t], vb = sv[ixj];
                int ia = si[t], ib = si[ixj];
                bool before = (va > vb) || (va == vb && ia < ib);  // stable: idx asc
                bool up = ((t & k) == 0);
                if (up ? !before : before) {
                    sv[t] = vb; sv[ixj] = va;
                    si[t] = ib; si[ixj] = ia;
                }
            }
            __syncthreads();
        }
    }
    if (t < KKEEP) {
        float v = sv[t];
        int idx = si[t];
        const float* hv = h2 + (size_t)(g * NGR + idx) * F1DIM;
        float acc = 0.f;
        for (int c = 0; c < F1DIM; c++) {
            float xc = __fmul_rn(hv[c], v);
            acc = fmaf(xc, wl[c], acc);
        }
        float z = __fadd_rn(acc, blin[0]);
        out[g * KKEEP + t] = (float)(1.0 / (1.0 + exp(-(double)z)));
    }
}

// ---------------------------------------------------------------------------
extern "C" void kernel_launch(void* const* d_in, const int* in_sizes, int n_in,
                              void* d_out, int out_size, void* d_ws, size_t ws_size,
                              hipStream_t stream) {
    const float* x        = (const float*)d_in[0];
    const int*   ei       = (const int*)d_in[1];
    const float* eattr    = (const float*)d_in[2];
    // d_in[3] = batch (unused; nodes are contiguous per graph)
    const float* Wl1  = (const float*)d_in[4];
    const float* bl1  = (const float*)d_in[5];
    const float* Wr1  = (const float*)d_in[6];
    const float* br1  = (const float*)d_in[7];
    const float* We1  = (const float*)d_in[8];
    const float* att1 = (const float*)d_in[9];
    const float* bout1= (const float*)d_in[10];
    const float* Wl2  = (const float*)d_in[11];
    const float* bl2  = (const float*)d_in[12];
    const float* Wr2  = (const float*)d_in[13];
    const float* br2  = (const float*)d_in[14];
    const float* We2  = (const float*)d_in[15];
    const float* att2 = (const float*)d_in[16];
    const float* bout2= (const float*)d_in[17];
    const float* Wrel = (const float*)d_in[18];
    const float* brel = (const float*)d_in[19];
    const float* Wroot= (const float*)d_in[20];
    const float* Wlin = (const float*)d_in[21];
    const float* blin = (const float*)d_in[22];
    float* out = (float*)d_out;

    // workspace carve
    char* p = (char*)d_ws;
    auto alloc = [&](size_t bytes) {
        void* r = (void*)p;
        p += (bytes + 255) & ~(size_t)255;
        return r;
    };
    int*   deg      = (int*)alloc(NNODES * 4);
    int*   rowstart = (int*)alloc((NNODES + 1) * 4);
    int*   fill     = (int*)alloc(NNODES * 4);
    int*   csr      = (int*)alloc(NEDGES * 4);
    float* loop_attr= (float*)alloc((size_t)NNODES * DEDGE * 4);
    float* bufA     = (float*)alloc((size_t)NNODES * F1DIM * 4);   // xl / aggv
    float* bufB     = (float*)alloc((size_t)NNODES * F1DIM * 4);   // xr
    float* bufC     = (float*)alloc((size_t)NNODES * F1DIM * 4);   // h1 then h2
    float* logitsB  = (float*)alloc((size_t)EATOT * 2 * 4);
    float* wB       = (float*)alloc((size_t)EATOT * 2 * 4);
    float* scoreV   = (float*)alloc(NNODES * 4);

    // CSR build (deterministic after sort)
    hipMemsetAsync(deg, 0, NNODES * 4, stream);
    count_kernel<<<NEDGES / 256, 256, 0, stream>>>(ei, deg);
    scan_kernel<<<1, 1024, 0, stream>>>(deg, rowstart, fill);
    scatter_kernel<<<NEDGES / 256, 256, 0, stream>>>(ei, fill, csr);
    sortcsr_kernel<<<NNODES / 256, 256, 0, stream>>>(rowstart, csr);
    loopattr_kernel<<<NNODES * DEDGE / 256, 256, 0, stream>>>(rowstart, csr, eattr, loop_attr);

    // ---- layer 1 (heads=2) ----
    gemm_lr_kernel<DNODE><<<NNODES / 16, 256, 0, stream>>>(x, Wl1, bl1, Wr1, br1, bufA, bufB);
    logits_kernel<2><<<2048, 256, 0, stream>>>(ei, eattr, loop_attr, bufA, bufB, We1, att1, logitsB);
    softmax_kernel<2><<<(NNODES * 2) / 256, 256, 0, stream>>>(rowstart, csr, logitsB, wB);
    agg_kernel<2, true><<<NNODES, 256, 0, stream>>>(ei, rowstart, csr, wB, bufA, bout1, bufC);

    // ---- layer 2 (heads=1) ----
    gemm_lr_kernel<F1DIM><<<NNODES / 16, 256, 0, stream>>>(bufC, Wl2, bl2, Wr2, br2, bufA, bufB);
    logits_kernel<1><<<2048, 256, 0, stream>>>(ei, eattr, loop_attr, bufA, bufB, We2, att2, logitsB);
    softmax_kernel<1><<<NNODES / 256, 256, 0, stream>>>(rowstart, csr, logitsB, wB);
    agg_kernel<1, false><<<NNODES, 256, 0, stream>>>(ei, rowstart, csr, wB, bufA, bout2, bufC);

    // ---- SAG pooling + head ----
    aggvec_kernel<<<NNODES, 256, 0, stream>>>(ei, rowstart, csr, bufC, bufA);
    score_dots_kernel<<<NNODES / 256, 256, 0, stream>>>(bufC, bufA, Wrel, Wroot, brel, scoreV);
    topk_kernel<<<NB, 256, 0, stream>>>(scoreV, bufC, Wlin, blin, out);
}